// Round 1
// baseline (3724.396 us; speedup 1.0000x reference)
//
#include <hip/hip_runtime.h>

// Problem constants
#define F_BINS 257
#define NCH    8
#define NSRC   2
#define KW     5
#define HCH    32
#define TLEN   2000
#define BATCH  4

// Tiling
#define TT   96
#define NT   ((TLEN + TT - 1) / TT)   // 21
#define XW   (TT + 12)                // x window (halo 6 each side)
#define H1W  (TT + 8)                 // h1 window (halo 4)
#define H2W  (TT + 4)                 // h2 window (halo 2)

// LDS layout (floats)
#define OFF_XR  0
#define OFF_XI  (OFF_XR  + NCH * XW)
#define OFF_H1R (OFF_XI  + NCH * XW)
#define OFF_H1I (OFF_H1R + HCH * H1W)
#define OFF_H2R (OFF_H1I + HCH * H1W)
#define OFF_H2I (OFF_H2R + HCH * H2W)
#define SMEM_FLOATS (OFF_H2I + HCH * H2W)   // 14784 floats = 59.1 KiB

__global__ __launch_bounds__(256) void cddcnn_kernel(
    const float* __restrict__ x,
    const float* __restrict__ Wr1, const float* __restrict__ Wi1,
    const float* __restrict__ Wr2, const float* __restrict__ Wi2,
    const float* __restrict__ Wr3, const float* __restrict__ Wi3,
    float* __restrict__ out)
{
    __shared__ float smem[SMEM_FLOATS];
    const int tid  = threadIdx.x;
    const int bid  = blockIdx.x;
    const int tile = bid % NT;
    const int f    = (bid / NT) % F_BINS;
    const int b    = bid / (NT * F_BINS);
    const int t0   = tile * TT;

    float* xr  = smem + OFF_XR;
    float* xi  = smem + OFF_XI;
    float* h1r = smem + OFF_H1R;
    float* h1i = smem + OFF_H1I;
    float* h2r = smem + OFF_H2R;
    float* h2i = smem + OFF_H2I;
    // h3 aliases h1 (dead after phase 2); 16*TT = 1536 <= 32*H1W = 3328
    float* h3r = smem + OFF_H1R;
    float* h3i = smem + OFF_H1I;

    // ---- Phase 0: stage x tile (zero-padded halo 6) ----
    const long xr_base = ((long)(b * 2 * F_BINS + f) * NCH) * TLEN;
    const long xi_base = ((long)(b * 2 * F_BINS + F_BINS + f) * NCH) * TLEN;
    for (int e = tid; e < NCH * XW; e += 256) {
        int c = e / XW, j = e % XW;
        int t = t0 - 6 + j;
        bool ok = (t >= 0) && (t < TLEN);
        xr[c * XW + j] = ok ? x[xr_base + (long)c * TLEN + t] : 0.f;
        xi[c * XW + j] = ok ? x[xi_base + (long)c * TLEN + t] : 0.f;
    }
    __syncthreads();

    // ---- Phase 1: h1 = relu(cconv(x, W1)), t = t0-4+j, j in [0,H1W) ----
    {
        const float* wr = Wr1 + (long)f * HCH * NCH * KW;
        const float* wi = Wi1 + (long)f * HCH * NCH * KW;
        const int NQ = H1W / 4;  // 26
        for (int e = tid; e < HCH * NQ; e += 256) {
            int h = e / NQ, j0 = (e % NQ) * 4;
            float ar[4] = {0,0,0,0}, ai[4] = {0,0,0,0};
            for (int c = 0; c < NCH; ++c) {
                float vr[8], vi[8];
                #pragma unroll
                for (int k = 0; k < 8; ++k) {
                    vr[k] = xr[c * XW + j0 + k];
                    vi[k] = xi[c * XW + j0 + k];
                }
                const float* wrc = wr + (h * NCH + c) * KW;
                const float* wic = wi + (h * NCH + c) * KW;
                #pragma unroll
                for (int w = 0; w < KW; ++w) {
                    float a = wrc[w], g = wic[w];
                    #pragma unroll
                    for (int k = 0; k < 4; ++k) {
                        ar[k] += a * vr[k + w] - g * vi[k + w];
                        ai[k] += g * vr[k + w] + a * vi[k + w];
                    }
                }
            }
            #pragma unroll
            for (int k = 0; k < 4; ++k) {
                int t = t0 - 4 + j0 + k;
                bool ok = (t >= 0) && (t < TLEN);
                h1r[h * H1W + j0 + k] = ok ? fmaxf(ar[k], 0.f) : 0.f;
                h1i[h * H1W + j0 + k] = ok ? fmaxf(ai[k], 0.f) : 0.f;
            }
        }
    }
    __syncthreads();

    // ---- Phase 2: h2 = relu(cconv(h1, W2)), t = t0-2+j, j in [0,H2W) ----
    {
        const float* wr = Wr2 + (long)f * HCH * HCH * KW;
        const float* wi = Wi2 + (long)f * HCH * HCH * KW;
        const int NQ = H2W / 4;  // 25
        for (int e = tid; e < HCH * NQ; e += 256) {
            int h = e / NQ, j0 = (e % NQ) * 4;
            float ar[4] = {0,0,0,0}, ai[4] = {0,0,0,0};
            for (int c = 0; c < HCH; ++c) {
                float vr[8], vi[8];
                #pragma unroll
                for (int k = 0; k < 8; ++k) {
                    vr[k] = h1r[c * H1W + j0 + k];
                    vi[k] = h1i[c * H1W + j0 + k];
                }
                const float* wrc = wr + (h * HCH + c) * KW;
                const float* wic = wi + (h * HCH + c) * KW;
                #pragma unroll
                for (int w = 0; w < KW; ++w) {
                    float a = wrc[w], g = wic[w];
                    #pragma unroll
                    for (int k = 0; k < 4; ++k) {
                        ar[k] += a * vr[k + w] - g * vi[k + w];
                        ai[k] += g * vr[k + w] + a * vi[k + w];
                    }
                }
            }
            #pragma unroll
            for (int k = 0; k < 4; ++k) {
                int t = t0 - 2 + j0 + k;
                bool ok = (t >= 0) && (t < TLEN);
                h2r[h * H2W + j0 + k] = ok ? fmaxf(ar[k], 0.f) : 0.f;
                h2i[h * H2W + j0 + k] = ok ? fmaxf(ai[k], 0.f) : 0.f;
            }
        }
    }
    __syncthreads();

    // ---- Phase 3: h3 = cconv(h2, W3) (no relu), t = t0+j, j in [0,TT) ----
    {
        const float* wr = Wr3 + (long)f * (NCH * NSRC) * HCH * KW;
        const float* wi = Wi3 + (long)f * (NCH * NSRC) * HCH * KW;
        const int NQ = TT / 4;  // 24
        // stash results in registers then write after sync? No: h3 aliases h1,
        // and phase 3 reads h2 only -> safe to write h3 now (h1 dead).
        for (int e = tid; e < (NCH * NSRC) * NQ; e += 256) {
            int o = e / NQ, j0 = (e % NQ) * 4;
            float ar[4] = {0,0,0,0}, ai[4] = {0,0,0,0};
            for (int c = 0; c < HCH; ++c) {
                float vr[8], vi[8];
                #pragma unroll
                for (int k = 0; k < 8; ++k) {
                    vr[k] = h2r[c * H2W + j0 + k];
                    vi[k] = h2i[c * H2W + j0 + k];
                }
                const float* wrc = wr + (o * HCH + c) * KW;
                const float* wic = wi + (o * HCH + c) * KW;
                #pragma unroll
                for (int w = 0; w < KW; ++w) {
                    float a = wrc[w], g = wic[w];
                    #pragma unroll
                    for (int k = 0; k < 4; ++k) {
                        ar[k] += a * vr[k + w] - g * vi[k + w];
                        ai[k] += g * vr[k + w] + a * vi[k + w];
                    }
                }
            }
            #pragma unroll
            for (int k = 0; k < 4; ++k) {
                int t = t0 + j0 + k;
                bool ok = (t < TLEN);
                h3r[o * TT + j0 + k] = ok ? ar[k] : 0.f;
                h3i[o * TT + j0 + k] = ok ? ai[k] : 0.f;
            }
        }
    }
    __syncthreads();

    // ---- Phase 4: mask-multiply + channel reduce + write ----
    // Yr[s,t] = sum_c xr[c,t]*h3r[c*2+s,t] - xi[c,t]*h3i[c*2+s,t]
    // Yi[s,t] = sum_c xr[c,t]*h3i[c*2+s,t] + xi[c,t]*h3r[c*2+s,t]
    for (int e = tid; e < NSRC * TT; e += 256) {
        int s = e / TT, j = e % TT;
        int t = t0 + j;
        if (t >= TLEN) continue;
        float Yr = 0.f, Yi = 0.f;
        #pragma unroll
        for (int c = 0; c < NCH; ++c) {
            float vr = xr[c * XW + j + 6];
            float vi = xi[c * XW + j + 6];
            float hr = h3r[(c * NSRC + s) * TT + j];
            float hi = h3i[(c * NSRC + s) * TT + j];
            Yr += vr * hr - vi * hi;
            Yi += vr * hi + vi * hr;
        }
        long or_idx = (((long)(b * 2 * F_BINS + f) * NSRC + s)) * TLEN + t;
        long oi_idx = (((long)(b * 2 * F_BINS + F_BINS + f) * NSRC + s)) * TLEN + t;
        out[or_idx] = Yr;
        out[oi_idx] = Yi;
    }
}

extern "C" void kernel_launch(void* const* d_in, const int* in_sizes, int n_in,
                              void* d_out, int out_size, void* d_ws, size_t ws_size,
                              hipStream_t stream) {
    const float* x   = (const float*)d_in[0];
    const float* Wr1 = (const float*)d_in[1];
    const float* Wi1 = (const float*)d_in[2];
    const float* Wr2 = (const float*)d_in[3];
    const float* Wi2 = (const float*)d_in[4];
    const float* Wr3 = (const float*)d_in[5];
    const float* Wi3 = (const float*)d_in[6];
    float* out = (float*)d_out;

    dim3 grid(BATCH * F_BINS * NT);
    dim3 block(256);
    cddcnn_kernel<<<grid, block, 0, stream>>>(x, Wr1, Wi1, Wr2, Wi2, Wr3, Wi3, out);
}

// Round 2
// 1350.121 us; speedup vs baseline: 2.7586x; 2.7586x over previous
//
#include <hip/hip_runtime.h>

// ---------------- problem constants ----------------
#define F_BINS 257
#define NCH    8
#define NSRC   2
#define KW     5
#define HCH    32
#define TLEN   2000
#define BATCH  4

// ---------------- tiling ----------------
#define TT      128
#define NTILES  16          // 16*128 = 2048 >= 2000

// LDS layout (bytes). x tile: 148 cols (halo 10 left / 10 right), 16 ch (+pad to 24)
#define XSTRIDE 24
#define XCOLS   148
#define XOFF    0
#define XSZ     (XCOLS * XSTRIDE * 2)          // 7104 B
#define HWIN    144                            // h1/h2 window: [t0-8, t0+136)
#define H1OFF   XSZ                            // 7104
#define HSZ     (HWIN * 64 * 2)                // 18432 B
#define H2OFF   (H1OFF + HSZ)                  // 25536
#define SMEM_BYTES (H2OFF + HSZ)               // 43968 B  (< 64 KiB static)
#define H3OFF   H1OFF                          // h3 aliases h1 (dead after L2)
#define H3STRIDE 40                            // fp16 per col (32 used + pad)

typedef _Float16 half8  __attribute__((ext_vector_type(8)));
typedef _Float16 half2t __attribute__((ext_vector_type(2)));
typedef float    f32x4  __attribute__((ext_vector_type(4)));

#define MFMA16(a, b, c) __builtin_amdgcn_mfma_f32_16x16x32_f16(a, b, c, 0, 0, 0)

__global__ __launch_bounds__(256, 2) void cddcnn_mfma_kernel(
    const float* __restrict__ x,
    const float* __restrict__ Wr1, const float* __restrict__ Wi1,
    const float* __restrict__ Wr2, const float* __restrict__ Wi2,
    const float* __restrict__ Wr3, const float* __restrict__ Wi3,
    float* __restrict__ out)
{
    __shared__ __align__(16) char sm[SMEM_BYTES];

    const int tid  = threadIdx.x;
    const int lane = tid & 63;
    const int wv   = tid >> 6;      // 0..3
    const int mw   = wv >> 1;       // 0: real-out rows, 1: imag-out rows
    const int nw   = wv & 1;        // n-half
    const int g    = lane >> 4;     // k-group 0..3
    const int r16  = lane & 15;     // A-row / B-col / D-col index

    const int f = blockIdx.x % F_BINS;
    const int b = blockIdx.x / F_BINS;

    // per-wave nb ranges over the 9-block (144-col) h1/h2 windows
    const int nb0 = nw ? 5 : 0;
    const int nbn = nw ? 4 : 5;

    // ------------------------------------------------------------------
    // Gather weight fragments into VGPRs (once per block, per wave).
    // A-frag lane map (16x16x32): A[row = lane&15][k = (lane>>4)*8 + j]
    // Rows: [real-out(0..31); imag-out(32..63)]; wave owns rows mw*32..+32.
    // k-order L2/L3: [h_real c0..31 | h_imag c0..31] (kk selects part).
    // k-order L1 (tap-pairs): groups g -> (tap = 2p+(g>>1), part = g&1).
    // Signs baked: real rows: coeff(xr)=Wr, coeff(xi)=-Wi; imag rows: Wi, Wr.
    // ------------------------------------------------------------------
    half8 a1[2][3];      // [hrange][pair]
    half8 a2[5][2][2];   // [tap][hrange][kk]
    half8 a3[5][2];      // [tap][kk]

    {
        #pragma unroll
        for (int hr = 0; hr < 2; ++hr)
        #pragma unroll
        for (int p = 0; p < 3; ++p) {
            half8 v;
            const int tap = 2 * p + (g >> 1);
            #pragma unroll
            for (int j = 0; j < 8; ++j) {
                float val = 0.f;
                if (tap < KW) {
                    long idx = (((long)f * HCH + hr * 16 + r16) * NCH + j) * KW + tap;
                    if (mw == 0) val = (g & 1) ? -Wi1[idx] : Wr1[idx];
                    else         val = (g & 1) ?  Wr1[idx] : Wi1[idx];
                }
                v[j] = (_Float16)val;
            }
            a1[hr][p] = v;
        }
        #pragma unroll
        for (int w = 0; w < KW; ++w)
        #pragma unroll
        for (int hr = 0; hr < 2; ++hr)
        #pragma unroll
        for (int kk = 0; kk < 2; ++kk) {
            half8 v;
            #pragma unroll
            for (int j = 0; j < 8; ++j) {
                int c = g * 8 + j;
                long idx = (((long)f * HCH + hr * 16 + r16) * HCH + c) * KW + w;
                float val;
                if (mw == 0) val = kk ? -Wi2[idx] : Wr2[idx];
                else         val = kk ?  Wr2[idx] : Wi2[idx];
                v[j] = (_Float16)val;
            }
            a2[w][hr][kk] = v;
        }
        #pragma unroll
        for (int w = 0; w < KW; ++w)
        #pragma unroll
        for (int kk = 0; kk < 2; ++kk) {
            half8 v;
            #pragma unroll
            for (int j = 0; j < 8; ++j) {
                int c = g * 8 + j;
                long idx = (((long)f * (NCH * NSRC) + r16) * HCH + c) * KW + w;
                float val;
                if (mw == 0) val = kk ? -Wi3[idx] : Wr3[idx];
                else         val = kk ?  Wr3[idx] : Wi3[idx];
                v[j] = (_Float16)val;
            }
            a3[w][kk] = v;
        }
    }

    const long xr_base = ((long)(b * 2 * F_BINS + f) * NCH) * TLEN;
    const long xi_base = ((long)(b * 2 * F_BINS + F_BINS + f) * NCH) * TLEN;

    for (int tl = 0; tl < NTILES; ++tl) {
        const int t0 = tl * TT;

        // ---- Phase X: stage x tile as fp16 [148 cols][16 ch], halo 10 ----
        for (int e = tid; e < XCOLS * 16; e += 256) {
            int pc  = e / XCOLS;          // 0..15 : part*8 + c
            int idx = e - pc * XCOLS;     // col in window
            int t   = t0 - 10 + idx;
            float val = 0.f;
            if (t >= 0 && t < TLEN) {
                long base = (pc < 8) ? (xr_base + (long)pc * TLEN)
                                     : (xi_base + (long)(pc - 8) * TLEN);
                val = x[base + t];
            }
            *(_Float16*)(sm + XOFF + (idx * XSTRIDE + pc) * 2) = (_Float16)val;
        }
        __syncthreads();

        // ---- Phase L1: h1 = relu(cconv(x, W1)) over 144-col window ----
        {
            f32x4 acc[2][5] = {};
            #pragma unroll
            for (int p = 0; p < 3; ++p) {
                int tap = 2 * p + (g >> 1);
                if (tap > 4) tap = 4;          // A is zero for these groups
                #pragma unroll
                for (int nbi = 0; nbi < 5; ++nbi) {
                    if (nbi < nbn) {
                        int col = (nb0 + nbi) * 16 + r16;   // h1 window col
                        int xi_ = col + tap;                // x window col
                        const half8 bf = *(const half8*)(sm + XOFF + (xi_ * XSTRIDE + (g & 1) * 8) * 2);
                        acc[0][nbi] = MFMA16(a1[0][p], bf, acc[0][nbi]);
                        acc[1][nbi] = MFMA16(a1[1][p], bf, acc[1][nbi]);
                    }
                }
            }
            #pragma unroll
            for (int hr = 0; hr < 2; ++hr)
            #pragma unroll
            for (int nbi = 0; nbi < 5; ++nbi) {
                if (nbi < nbn) {
                    int col = (nb0 + nbi) * 16 + r16;
                    int t = t0 - 8 + col;
                    bool ok = (t >= 0) && (t < TLEN);
                    #pragma unroll
                    for (int q = 0; q < 2; ++q) {
                        float v0 = ok ? fmaxf(acc[hr][nbi][2 * q],     0.f) : 0.f;
                        float v1 = ok ? fmaxf(acc[hr][nbi][2 * q + 1], 0.f) : 0.f;
                        int m = mw * 32 + hr * 16 + g * 4 + 2 * q;
                        int addr = H1OFF + (((col * 64 + m) * 2) ^ ((col & 7) << 4));
                        half2t hv; hv[0] = (_Float16)v0; hv[1] = (_Float16)v1;
                        *(half2t*)(sm + addr) = hv;
                    }
                }
            }
        }
        __syncthreads();

        // ---- Phase L2: h2 = relu(cconv(h1, W2)) over 144-col window ----
        {
            f32x4 acc[2][5] = {};
            #pragma unroll
            for (int w = 0; w < KW; ++w)
            #pragma unroll
            for (int kk = 0; kk < 2; ++kk) {
                #pragma unroll
                for (int nbi = 0; nbi < 5; ++nbi) {
                    if (nbi < nbn) {
                        int col = (nb0 + nbi) * 16 + r16;
                        int src = col + w - 2;              // h1 window col
                        int addr = H1OFF + (((src * 64 + kk * 32 + g * 8) * 2) ^ ((src & 7) << 4));
                        const half8 bf = *(const half8*)(sm + addr);
                        acc[0][nbi] = MFMA16(a2[w][0][kk], bf, acc[0][nbi]);
                        acc[1][nbi] = MFMA16(a2[w][1][kk], bf, acc[1][nbi]);
                    }
                }
            }
            #pragma unroll
            for (int hr = 0; hr < 2; ++hr)
            #pragma unroll
            for (int nbi = 0; nbi < 5; ++nbi) {
                if (nbi < nbn) {
                    int col = (nb0 + nbi) * 16 + r16;
                    int t = t0 - 8 + col;
                    bool ok = (t >= 0) && (t < TLEN);
                    #pragma unroll
                    for (int q = 0; q < 2; ++q) {
                        float v0 = ok ? fmaxf(acc[hr][nbi][2 * q],     0.f) : 0.f;
                        float v1 = ok ? fmaxf(acc[hr][nbi][2 * q + 1], 0.f) : 0.f;
                        int m = mw * 32 + hr * 16 + g * 4 + 2 * q;
                        int addr = H2OFF + (((col * 64 + m) * 2) ^ ((col & 7) << 4));
                        half2t hv; hv[0] = (_Float16)v0; hv[1] = (_Float16)v1;
                        *(half2t*)(sm + addr) = hv;
                    }
                }
            }
        }
        __syncthreads();

        // ---- Phase L3: h3 = cconv(h2, W3) (no relu), 128 cols ----
        {
            f32x4 acc3[4] = {};
            #pragma unroll
            for (int w = 0; w < KW; ++w)
            #pragma unroll
            for (int kk = 0; kk < 2; ++kk) {
                #pragma unroll
                for (int nbi = 0; nbi < 4; ++nbi) {
                    int col = nw * 64 + nbi * 16 + r16;     // h3 col 0..127
                    int src = col + 6 + w;                  // h2 window col (6..137)
                    int addr = H2OFF + (((src * 64 + kk * 32 + g * 8) * 2) ^ ((src & 7) << 4));
                    const half8 bf = *(const half8*)(sm + addr);
                    acc3[nbi] = MFMA16(a3[w][kk], bf, acc3[nbi]);
                }
            }
            #pragma unroll
            for (int nbi = 0; nbi < 4; ++nbi) {
                int col = nw * 64 + nbi * 16 + r16;
                #pragma unroll
                for (int q = 0; q < 2; ++q) {
                    int och = mw * 16 + g * 4 + 2 * q;      // 0..15 real, 16..31 imag
                    int addr = H3OFF + col * (H3STRIDE * 2) + och * 2;
                    half2t hv;
                    hv[0] = (_Float16)acc3[nbi][2 * q];
                    hv[1] = (_Float16)acc3[nbi][2 * q + 1];
                    *(half2t*)(sm + addr) = hv;
                }
            }
        }
        __syncthreads();

        // ---- Phase M: mask multiply + channel reduce + store ----
        if (tid < TT) {
            int col = tid;
            int t = t0 + col;
            if (t < TLEN) {
                const half8 xrv = *(const half8*)(sm + XOFF + ((col + 10) * XSTRIDE + 0) * 2);
                const half8 xiv = *(const half8*)(sm + XOFF + ((col + 10) * XSTRIDE + 8) * 2);
                half8 h3q[4];
                #pragma unroll
                for (int q = 0; q < 4; ++q)
                    h3q[q] = *(const half8*)(sm + H3OFF + col * (H3STRIDE * 2) + q * 16);
                float Yr[2] = {0.f, 0.f}, Yi[2] = {0.f, 0.f};
                #pragma unroll
                for (int c = 0; c < NCH; ++c) {
                    float vr = (float)xrv[c];
                    float vi = (float)xiv[c];
                    #pragma unroll
                    for (int s = 0; s < NSRC; ++s) {
                        int o = 2 * c + s;                  // 0..15
                        float hr = (o < 8) ? (float)h3q[0][o] : (float)h3q[1][o - 8];
                        float hi = (o < 8) ? (float)h3q[2][o] : (float)h3q[3][o - 8];
                        Yr[s] += vr * hr - vi * hi;
                        Yi[s] += vr * hi + vi * hr;
                    }
                }
                #pragma unroll
                for (int s = 0; s < NSRC; ++s) {
                    out[((long)(b * 2 * F_BINS + f) * NSRC + s) * TLEN + t]          = Yr[s];
                    out[((long)(b * 2 * F_BINS + F_BINS + f) * NSRC + s) * TLEN + t] = Yi[s];
                }
            }
        }
        __syncthreads();
    }
}

extern "C" void kernel_launch(void* const* d_in, const int* in_sizes, int n_in,
                              void* d_out, int out_size, void* d_ws, size_t ws_size,
                              hipStream_t stream) {
    const float* x   = (const float*)d_in[0];
    const float* Wr1 = (const float*)d_in[1];
    const float* Wi1 = (const float*)d_in[2];
    const float* Wr2 = (const float*)d_in[3];
    const float* Wi2 = (const float*)d_in[4];
    const float* Wr3 = (const float*)d_in[5];
    const float* Wi3 = (const float*)d_in[6];
    float* out = (float*)d_out;

    dim3 grid(BATCH * F_BINS);
    dim3 block(256);
    cddcnn_mfma_kernel<<<grid, block, 0, stream>>>(x, Wr1, Wi1, Wr2, Wi2, Wr3, Wi3, out);
}

// Round 3
// 317.976 us; speedup vs baseline: 11.7128x; 4.2460x over previous
//
#include <hip/hip_runtime.h>

// ---------------- problem constants ----------------
#define F_BINS 257
#define NCH    8
#define NSRC   2
#define KW     5
#define HCH    32
#define TLEN   2000
#define BATCH  4

// ---------------- tiling ----------------
#define TT      128
#define NTILES  16          // 16*128 = 2048 >= 2000

// LDS layout (bytes). x tile: 148 cols (halo 10 left / 10 right), 16 ch (pad to 24)
#define XSTRIDE 24
#define XCOLS   148
#define XOFF    0
#define XSZ     (XCOLS * XSTRIDE * 2)          // 7104 B
#define HWIN    144                            // h1/h2 window: [t0-8, t0+136)
#define H1OFF   XSZ
#define HSZ     (HWIN * 64 * 2)                // 18432 B
#define H2OFF   (H1OFF + HSZ)
#define SMEM_BYTES (H2OFF + HSZ)               // 43968 B
#define H3OFF   H1OFF                          // h3 aliases h1 (dead after L2)
#define H3STRIDE 40                            // halfs per col (32 used + pad)

// packed weight fragments: [f][frag*2+mw][lane] of half8 (16B each)
#define NFRAG   36
#define PW_HALF8_PER_F (NFRAG * 2 * 64)
#define PW_BYTES ((size_t)F_BINS * PW_HALF8_PER_F * 16)   // ~18.9 MB

typedef _Float16 half8  __attribute__((ext_vector_type(8)));
typedef _Float16 half2t __attribute__((ext_vector_type(2)));
typedef float    f32x4  __attribute__((ext_vector_type(4)));

#define MFMA16(a, b, c) __builtin_amdgcn_mfma_f32_16x16x32_f16(a, b, c, 0, 0, 0)

// frag ids: a1[hr][p] = hr*3+p (0..5); a2[w][hr][kk] = 6+w*4+hr*2+kk (6..25);
//           a3[w][kk] = 26+w*2+kk (26..35)
__device__ __forceinline__ half8 gather_frag(
    int f, int frag, int mw, int lane,
    const float* __restrict__ Wr1, const float* __restrict__ Wi1,
    const float* __restrict__ Wr2, const float* __restrict__ Wi2,
    const float* __restrict__ Wr3, const float* __restrict__ Wi3)
{
    const int g = lane >> 4, r16 = lane & 15;
    half8 v;
    if (frag < 6) {
        int hr = frag / 3, p = frag % 3;
        int tap = 2 * p + (g >> 1);
        #pragma unroll
        for (int j = 0; j < 8; ++j) {
            float val = 0.f;
            if (tap < KW) {
                long idx = (((long)f * HCH + hr * 16 + r16) * NCH + j) * KW + tap;
                if (mw == 0) val = (g & 1) ? -Wi1[idx] : Wr1[idx];
                else         val = (g & 1) ?  Wr1[idx] : Wi1[idx];
            }
            v[j] = (_Float16)val;
        }
    } else if (frag < 26) {
        int u = frag - 6;
        int w = u >> 2, hr = (u >> 1) & 1, kk = u & 1;
        #pragma unroll
        for (int j = 0; j < 8; ++j) {
            int c = g * 8 + j;
            long idx = (((long)f * HCH + hr * 16 + r16) * HCH + c) * KW + w;
            float val;
            if (mw == 0) val = kk ? -Wi2[idx] : Wr2[idx];
            else         val = kk ?  Wr2[idx] : Wi2[idx];
            v[j] = (_Float16)val;
        }
    } else {
        int u = frag - 26;
        int w = u >> 1, kk = u & 1;
        #pragma unroll
        for (int j = 0; j < 8; ++j) {
            int c = g * 8 + j;
            long idx = (((long)f * (NCH * NSRC) + r16) * HCH + c) * KW + w;
            float val;
            if (mw == 0) val = kk ? -Wi3[idx] : Wr3[idx];
            else         val = kk ?  Wr3[idx] : Wi3[idx];
            v[j] = (_Float16)val;
        }
    }
    return v;
}

__global__ __launch_bounds__(256) void repack_kernel(
    const float* __restrict__ Wr1, const float* __restrict__ Wi1,
    const float* __restrict__ Wr2, const float* __restrict__ Wi2,
    const float* __restrict__ Wr3, const float* __restrict__ Wi3,
    _Float16* __restrict__ pw)
{
    const int bid  = blockIdx.x;
    const int f    = bid >> 2;
    const int part = bid & 3;
    const int lane = threadIdx.x & 63;
    const int q    = threadIdx.x >> 6;
    half8* pwv = (half8*)pw;
    for (int u = part * 18 + q; u < part * 18 + 18; u += 4) {
        int frag = u >> 1, mw = u & 1;
        half8 v = gather_frag(f, frag, mw, lane, Wr1, Wi1, Wr2, Wi2, Wr3, Wi3);
        pwv[((size_t)f * (NFRAG * 2) + u) * 64 + lane] = v;
    }
}

template<bool PACKED>
__global__ __launch_bounds__(256, 3) void cddcnn_mfma_kernel(
    const float* __restrict__ x,
    const float* __restrict__ Wr1, const float* __restrict__ Wi1,
    const float* __restrict__ Wr2, const float* __restrict__ Wi2,
    const float* __restrict__ Wr3, const float* __restrict__ Wi3,
    float* __restrict__ out, const _Float16* __restrict__ pw)
{
    __shared__ __align__(16) char sm[SMEM_BYTES];

    const int tid  = threadIdx.x;
    const int lane = tid & 63;
    const int wv   = tid >> 6;
    const int mw   = wv >> 1;       // 0: real-out rows, 1: imag-out rows
    const int nw   = wv & 1;        // n-half
    const int g    = lane >> 4;
    const int r16  = lane & 15;

    const int bid = blockIdx.x;
    const int tl  = bid % NTILES;
    const int f   = (bid / NTILES) % F_BINS;
    const int b   = bid / (NTILES * F_BINS);
    const int t0  = tl * TT;

    const int nb0 = nw ? 5 : 0;
    const int nbn = nw ? 4 : 5;

    const half8* pwf = PACKED ? ((const half8*)pw) + (size_t)f * PW_HALF8_PER_F + mw * 64 + lane
                              : nullptr;
    #define LOADFRAG(fr) (PACKED ? pwf[(fr) * 128] \
                                 : gather_frag(f, (fr), mw, lane, Wr1, Wi1, Wr2, Wi2, Wr3, Wi3))

    const long xr_base = ((long)(b * 2 * F_BINS + f) * NCH) * TLEN;
    const long xi_base = ((long)(b * 2 * F_BINS + F_BINS + f) * NCH) * TLEN;

    // ---- Phase X: stage x tile as fp16 [148 cols][16 ch], halo 10 ----
    for (int e = tid; e < XCOLS * 16; e += 256) {
        int pc  = e / XCOLS;
        int idx = e - pc * XCOLS;
        int t   = t0 - 10 + idx;
        float val = 0.f;
        if (t >= 0 && t < TLEN) {
            long base = (pc < 8) ? (xr_base + (long)pc * TLEN)
                                 : (xi_base + (long)(pc - 8) * TLEN);
            val = x[base + t];
        }
        *(_Float16*)(sm + XOFF + (idx * XSTRIDE + pc) * 2) = (_Float16)val;
    }
    __syncthreads();

    // ---- Phase L1: h1 = relu(cconv(x, W1)) over 144-col window ----
    {
        half8 a1[2][3];
        #pragma unroll
        for (int hr = 0; hr < 2; ++hr)
        #pragma unroll
        for (int p = 0; p < 3; ++p)
            a1[hr][p] = LOADFRAG(hr * 3 + p);

        f32x4 acc[2][5] = {};
        #pragma unroll
        for (int p = 0; p < 3; ++p) {
            int tap = 2 * p + (g >> 1);
            if (tap > 4) tap = 4;          // A is zero for these groups
            #pragma unroll
            for (int nbi = 0; nbi < 5; ++nbi) {
                if (nbi < nbn) {
                    int col = (nb0 + nbi) * 16 + r16;
                    int xi_ = col + tap;
                    const half8 bf = *(const half8*)(sm + XOFF + (xi_ * XSTRIDE + (g & 1) * 8) * 2);
                    acc[0][nbi] = MFMA16(a1[0][p], bf, acc[0][nbi]);
                    acc[1][nbi] = MFMA16(a1[1][p], bf, acc[1][nbi]);
                }
            }
        }
        #pragma unroll
        for (int hr = 0; hr < 2; ++hr)
        #pragma unroll
        for (int nbi = 0; nbi < 5; ++nbi) {
            if (nbi < nbn) {
                int col = (nb0 + nbi) * 16 + r16;
                int t = t0 - 8 + col;
                bool ok = (t >= 0) && (t < TLEN);
                #pragma unroll
                for (int q = 0; q < 2; ++q) {
                    float v0 = ok ? fmaxf(acc[hr][nbi][2 * q],     0.f) : 0.f;
                    float v1 = ok ? fmaxf(acc[hr][nbi][2 * q + 1], 0.f) : 0.f;
                    int m = mw * 32 + hr * 16 + g * 4 + 2 * q;
                    int addr = H1OFF + (((col * 64 + m) * 2) ^ ((col & 7) << 4));
                    half2t hv; hv[0] = (_Float16)v0; hv[1] = (_Float16)v1;
                    *(half2t*)(sm + addr) = hv;
                }
            }
        }
    }
    __syncthreads();

    // ---- Phase L2: h2 = relu(cconv(h1, W2)) over 144-col window ----
    {
        half8 a2[5][2][2];
        #pragma unroll
        for (int w = 0; w < KW; ++w)
        #pragma unroll
        for (int hr = 0; hr < 2; ++hr)
        #pragma unroll
        for (int kk = 0; kk < 2; ++kk)
            a2[w][hr][kk] = LOADFRAG(6 + w * 4 + hr * 2 + kk);

        f32x4 acc[2][5] = {};
        #pragma unroll
        for (int w = 0; w < KW; ++w)
        #pragma unroll
        for (int kk = 0; kk < 2; ++kk) {
            #pragma unroll
            for (int nbi = 0; nbi < 5; ++nbi) {
                if (nbi < nbn) {
                    int col = (nb0 + nbi) * 16 + r16;
                    int src = col + w - 2;
                    int addr = H1OFF + (((src * 64 + kk * 32 + g * 8) * 2) ^ ((src & 7) << 4));
                    const half8 bf = *(const half8*)(sm + addr);
                    acc[0][nbi] = MFMA16(a2[w][0][kk], bf, acc[0][nbi]);
                    acc[1][nbi] = MFMA16(a2[w][1][kk], bf, acc[1][nbi]);
                }
            }
        }
        #pragma unroll
        for (int hr = 0; hr < 2; ++hr)
        #pragma unroll
        for (int nbi = 0; nbi < 5; ++nbi) {
            if (nbi < nbn) {
                int col = (nb0 + nbi) * 16 + r16;
                int t = t0 - 8 + col;
                bool ok = (t >= 0) && (t < TLEN);
                #pragma unroll
                for (int q = 0; q < 2; ++q) {
                    float v0 = ok ? fmaxf(acc[hr][nbi][2 * q],     0.f) : 0.f;
                    float v1 = ok ? fmaxf(acc[hr][nbi][2 * q + 1], 0.f) : 0.f;
                    int m = mw * 32 + hr * 16 + g * 4 + 2 * q;
                    int addr = H2OFF + (((col * 64 + m) * 2) ^ ((col & 7) << 4));
                    half2t hv; hv[0] = (_Float16)v0; hv[1] = (_Float16)v1;
                    *(half2t*)(sm + addr) = hv;
                }
            }
        }
    }
    __syncthreads();

    // ---- Phase L3: h3 = cconv(h2, W3) (no relu), 128 cols ----
    {
        half8 a3[5][2];
        #pragma unroll
        for (int w = 0; w < KW; ++w)
        #pragma unroll
        for (int kk = 0; kk < 2; ++kk)
            a3[w][kk] = LOADFRAG(26 + w * 2 + kk);

        f32x4 acc3[4] = {};
        #pragma unroll
        for (int w = 0; w < KW; ++w)
        #pragma unroll
        for (int kk = 0; kk < 2; ++kk) {
            #pragma unroll
            for (int nbi = 0; nbi < 4; ++nbi) {
                int col = nw * 64 + nbi * 16 + r16;
                int src = col + 6 + w;
                int addr = H2OFF + (((src * 64 + kk * 32 + g * 8) * 2) ^ ((src & 7) << 4));
                const half8 bf = *(const half8*)(sm + addr);
                acc3[nbi] = MFMA16(a3[w][kk], bf, acc3[nbi]);
            }
        }
        #pragma unroll
        for (int nbi = 0; nbi < 4; ++nbi) {
            int col = nw * 64 + nbi * 16 + r16;
            #pragma unroll
            for (int q = 0; q < 2; ++q) {
                int och = mw * 16 + g * 4 + 2 * q;
                int addr = H3OFF + col * (H3STRIDE * 2) + och * 2;
                half2t hv;
                hv[0] = (_Float16)acc3[nbi][2 * q];
                hv[1] = (_Float16)acc3[nbi][2 * q + 1];
                *(half2t*)(sm + addr) = hv;
            }
        }
    }
    __syncthreads();

    // ---- Phase M: mask multiply + channel reduce + store (all 256 threads) ----
    {
        int s   = tid >> 7;         // 0..1
        int col = tid & 127;
        int t = t0 + col;
        if (t < TLEN) {
            const half8 xrv = *(const half8*)(sm + XOFF + ((col + 10) * XSTRIDE + 0) * 2);
            const half8 xiv = *(const half8*)(sm + XOFF + ((col + 10) * XSTRIDE + 8) * 2);
            half8 h3q[4];
            #pragma unroll
            for (int q = 0; q < 4; ++q)
                h3q[q] = *(const half8*)(sm + H3OFF + col * (H3STRIDE * 2) + q * 16);
            float Yr = 0.f, Yi = 0.f;
            #pragma unroll
            for (int c = 0; c < NCH; ++c) {
                float vr = (float)xrv[c];
                float vi = (float)xiv[c];
                int o = 2 * c + s;
                float hr = (c < 4) ? (float)h3q[0][o] : (float)h3q[1][o - 8];
                float hi = (c < 4) ? (float)h3q[2][o] : (float)h3q[3][o - 8];
                Yr += vr * hr - vi * hi;
                Yi += vr * hi + vi * hr;
            }
            out[((long)(b * 2 * F_BINS + f) * NSRC + s) * TLEN + t]          = Yr;
            out[((long)(b * 2 * F_BINS + F_BINS + f) * NSRC + s) * TLEN + t] = Yi;
        }
    }
}

extern "C" void kernel_launch(void* const* d_in, const int* in_sizes, int n_in,
                              void* d_out, int out_size, void* d_ws, size_t ws_size,
                              hipStream_t stream) {
    const float* x   = (const float*)d_in[0];
    const float* Wr1 = (const float*)d_in[1];
    const float* Wi1 = (const float*)d_in[2];
    const float* Wr2 = (const float*)d_in[3];
    const float* Wi2 = (const float*)d_in[4];
    const float* Wr3 = (const float*)d_in[5];
    const float* Wi3 = (const float*)d_in[6];
    float* out = (float*)d_out;

    dim3 block(256);
    dim3 grid(BATCH * F_BINS * NTILES);
    if (ws_size >= PW_BYTES) {
        _Float16* pw = (_Float16*)d_ws;
        repack_kernel<<<F_BINS * 4, block, 0, stream>>>(Wr1, Wi1, Wr2, Wi2, Wr3, Wi3, pw);
        cddcnn_mfma_kernel<true><<<grid, block, 0, stream>>>(
            x, Wr1, Wi1, Wr2, Wi2, Wr3, Wi3, out, pw);
    } else {
        cddcnn_mfma_kernel<false><<<grid, block, 0, stream>>>(
            x, Wr1, Wi1, Wr2, Wi2, Wr3, Wi3, out, nullptr);
    }
}